// Round 1
// 2520.577 us; speedup vs baseline: 1.2242x; 1.2242x over previous
//
#include <hip/hip_runtime.h>
#include <cstdint>
#include <cstddef>

typedef __bf16 bf16;
typedef __bf16 bf16x8 __attribute__((ext_vector_type(8)));
typedef float f32x4 __attribute__((ext_vector_type(4)));

#define SEQ 2048
#define DIM 4096
#define NHEAD 16
#define HDIM 256
#define DFF_N 16384
#define D3 12288
#define DHALF 8192

// ---------------- fused LayerNorm (ln1 + ln2) ----------------
__global__ __launch_bounds__(256) void ln_kernel(
    const float* __restrict__ x,
    const float* __restrict__ w1, const float* __restrict__ b1,
    const float* __restrict__ w2, const float* __restrict__ b2,
    bf16* __restrict__ x1, bf16* __restrict__ x2)
{
  int row = blockIdx.x;
  int t = threadIdx.x;
  const float* xr = x + (size_t)row * DIM + t * 16;
  float v[16];
  float s = 0.f, sq = 0.f;
#pragma unroll
  for (int i = 0; i < 4; i++) {
    float4 f = ((const float4*)xr)[i];
    v[i*4+0] = f.x; v[i*4+1] = f.y; v[i*4+2] = f.z; v[i*4+3] = f.w;
  }
#pragma unroll
  for (int i = 0; i < 16; i++) { s += v[i]; sq += v[i]*v[i]; }
#pragma unroll
  for (int o = 32; o; o >>= 1) { s += __shfl_xor(s, o, 64); sq += __shfl_xor(sq, o, 64); }
  __shared__ float rs[4], rq[4];
  int wave = t >> 6, lane = t & 63;
  if (lane == 0) { rs[wave] = s; rq[wave] = sq; }
  __syncthreads();
  s  = rs[0] + rs[1] + rs[2] + rs[3];
  sq = rq[0] + rq[1] + rq[2] + rq[3];
  float mean = s * (1.f/DIM);
  float var  = sq * (1.f/DIM) - mean*mean;
  float rstd = rsqrtf(var + 1e-5f);
  int c0 = t*16;
#pragma unroll
  for (int i = 0; i < 16; i++) {
    int c = c0 + i;
    float nv = (v[i] - mean) * rstd;
    x1[(size_t)row*DIM + c] = (bf16)(nv * w1[c] + b1[c]);
    x2[(size_t)row*DIM + c] = (bf16)(nv * w2[c] + b2[c]);
  }
}

// ---------------- transpose+convert: out[n][k] = (bf16) in[k][n] ----------
// Handles a [k0 : k0+gx*64) x [n0 : n0+gy*64) slice; out is the slice with
// leading dim ldout (= k-extent of the slice).
__global__ __launch_bounds__(256) void transpose_kernel(
    const float* __restrict__ in, bf16* __restrict__ out,
    int ldin, int k0, int n0, int ldout)
{
  __shared__ float tile[64][65];   // +1 pad: store-read is 2-way at worst
  const int t = threadIdx.x;
  const int kb = k0 + blockIdx.x * 64;
  const int nb = n0 + blockIdx.y * 64;
#pragma unroll
  for (int i = 0; i < 4; i++) {
    int c = t + i * 256;                  // 1024 float4 chunks
    int r = c >> 4, c4 = (c & 15) * 4;
    float4 v = *(const float4*)(in + (size_t)(kb + r) * ldin + nb + c4);
    tile[r][c4+0] = v.x; tile[r][c4+1] = v.y;
    tile[r][c4+2] = v.z; tile[r][c4+3] = v.w;
  }
  __syncthreads();
#pragma unroll
  for (int i = 0; i < 2; i++) {
    int c = t + i * 256;                  // 512 bf16x8 chunks
    int n = c >> 3, k8 = (c & 7) * 8;
    bf16x8 o;
#pragma unroll
    for (int j = 0; j < 8; j++) o[j] = (bf16)tile[k8 + j][n];
    *(bf16x8*)(out + (size_t)(blockIdx.y * 64 + n) * ldout + blockIdx.x * 64 + k8) = o;
  }
}

// ---------------- GEMM (m97 structure): C = A(bf16,[M,K]) * BT(bf16,[N,K])^T
// 128x128 tile, BK=32, global_load_lds width-16 staging, ds_read_b128 frags.
// EPI: 0 = bias -> bf16        (QKV)
//      1 = bias -> f32         (dense -> dense_o)
//      2 = bias+gelu -> bf16   (fc1 halves -> h1)
//      3 = bias+add1+add2 -> f32 (fc2 half0 -> out)
//      4 = accumulate: out += acc (fc2 half1)
template <int EPI>
__global__ __launch_bounds__(256) void gemm_kernel(
    const bf16* __restrict__ A, const bf16* __restrict__ BT,
    const float* __restrict__ bias,
    const float* __restrict__ add1, const float* __restrict__ add2,
    void* __restrict__ Cout, int M, int N, int K)
{
  __shared__ __align__(16) bf16 As[128 * 32];
  __shared__ __align__(16) bf16 Bs[128 * 32];
  const int t = threadIdx.x;
  const int lane = t & 63;
  const int wave = t >> 6;
  const int l15 = lane & 15, l4 = lane >> 4;

  // XCD-aware swizzle: contiguous chunk of blocks per XCD (all grids %8==0).
  const int nwgx = gridDim.x;
  const int nwg = nwgx * gridDim.y;
  const int orig = blockIdx.y * nwgx + blockIdx.x;
  const int cpx = nwg >> 3;
  const int swz = (orig & 7) * cpx + (orig >> 3);
  const int m0 = (swz % nwgx) * 128;   // m fastest within chunk -> share B panel
  const int n0 = (swz / nwgx) * 128;

  const int wm = (wave >> 1) * 64;
  const int wn = (wave & 1) * 64;

  f32x4 acc[4][4];
#pragma unroll
  for (int i = 0; i < 4; i++)
#pragma unroll
    for (int j = 0; j < 4; j++) acc[i][j] = (f32x4){0.f, 0.f, 0.f, 0.f};

  const bf16* Abase = A + (size_t)m0 * K;
  const bf16* Bbase = BT + (size_t)n0 * K;
  // per-thread staging coords: chunk c covers LDS bytes [c*16, c*16+16)
  // row = c>>2 (64 B per row), seg = (c&3)*8 bf16
  for (int k0 = 0; k0 < K; k0 += 32) {
#pragma unroll
    for (int i = 0; i < 2; i++) {
      int c = t + i * 256;
      int row = c >> 2, seg = (c & 3) * 8;
      __builtin_amdgcn_global_load_lds(
          (const __attribute__((address_space(1))) void*)(Abase + (size_t)row * K + k0 + seg),
          (__attribute__((address_space(3))) void*)(As + c * 8), 16, 0, 0);
      __builtin_amdgcn_global_load_lds(
          (const __attribute__((address_space(1))) void*)(Bbase + (size_t)row * K + k0 + seg),
          (__attribute__((address_space(3))) void*)(Bs + c * 8), 16, 0, 0);
    }
    __syncthreads();

    bf16x8 af[4], bfv[4];
#pragma unroll
    for (int mi = 0; mi < 4; mi++)
      af[mi] = *(const bf16x8*)(As + (wm + mi * 16 + l15) * 32 + l4 * 8);
#pragma unroll
    for (int ni = 0; ni < 4; ni++)
      bfv[ni] = *(const bf16x8*)(Bs + (wn + ni * 16 + l15) * 32 + l4 * 8);
#pragma unroll
    for (int ni = 0; ni < 4; ni++)
#pragma unroll
      for (int mi = 0; mi < 4; mi++)
        acc[mi][ni] = __builtin_amdgcn_mfma_f32_16x16x32_bf16(af[mi], bfv[ni], acc[mi][ni], 0, 0, 0);
    __syncthreads();
  }

  // epilogue; D layout: col = lane&15, row = (lane>>4)*4 + r  [verified m89/m91]
#pragma unroll
  for (int mi = 0; mi < 4; mi++) {
#pragma unroll
    for (int ni = 0; ni < 4; ni++) {
#pragma unroll
      for (int r = 0; r < 4; r++) {
        int m = m0 + wm + mi * 16 + l4 * 4 + r;
        int n = n0 + wn + ni * 16 + l15;
        size_t idx = (size_t)m * N + n;
        float val = acc[mi][ni][r];
        if (EPI == 0) {
          ((bf16*)Cout)[idx] = (bf16)(val + bias[n]);
        } else if (EPI == 1) {
          ((float*)Cout)[idx] = val + bias[n];
        } else if (EPI == 2) {
          // gelu_new (tanh approx); tanh via 1 - 2/(e^{2u}+1), overflow-safe
          float g = val + bias[n];
          float u = 0.7978845608028654f * (g + 0.044715f * g * g * g);
          float e = __expf(2.f * u);
          float th = 1.f - 2.f / (e + 1.f);
          ((bf16*)Cout)[idx] = (bf16)(0.5f * g * (1.f + th));
        } else if (EPI == 3) {
          ((float*)Cout)[idx] = val + bias[n] + add1[idx] + add2[idx];
        } else {
          ((float*)Cout)[idx] += val;
        }
      }
    }
  }
}

// ---------------- causal attention, one (16-query tile, head) per block ------
// LDS: scores fp32 [16][2049] (131 KB, dynamic) + inv_sum[16]
__global__ __launch_bounds__(256) void attn_kernel(
    const bf16* __restrict__ qkv, bf16* __restrict__ attn)
{
  extern __shared__ float smem[];
  float (*sc)[2049] = (float (*)[2049])smem;
  float* inv = smem + 16 * 2049;

  const int qt = blockIdx.x;   // 0..127
  const int h  = blockIdx.y;   // 0..15
  const int q0 = qt * 16;
  const int t = threadIdx.x;
  const int lane = t & 63, w = t >> 6;
  const int l15 = lane & 15, l4 = lane >> 4;

  // Q fragments (A-operand layout: m = lane&15, k = (lane>>4)*8 + j)
  bf16x8 qf[8];
  {
    const bf16* qbase = qkv + (size_t)(q0 + l15) * D3 + h * HDIM + l4 * 8;
#pragma unroll
    for (int dt = 0; dt < 8; dt++)
      qf[dt] = *(const bf16x8*)(qbase + dt * 32);
  }

  // ---- scores: waves split key tiles round-robin ----
  for (int kt = w; kt <= qt; kt += 4) {
    int k0 = kt * 16;
    f32x4 a = (f32x4){0.f, 0.f, 0.f, 0.f};
    const bf16* kbase = qkv + (size_t)(k0 + l15) * D3 + DIM + h * HDIM + l4 * 8;
#pragma unroll
    for (int dt = 0; dt < 8; dt++) {
      bf16x8 kf = *(const bf16x8*)(kbase + dt * 32);
      a = __builtin_amdgcn_mfma_f32_16x16x32_bf16(qf[dt], kf, a, 0, 0, 0);
    }
#pragma unroll
    for (int r = 0; r < 4; r++) {
      int qrow = l4 * 4 + r;          // query within tile
      int kcol = k0 + l15;            // global key
      float sv = a[r] * 0.0625f;      // HD^-0.5 = 1/16
      if (kcol > q0 + qrow) sv = -1e30f;
      sc[qrow][kcol] = sv;
    }
  }
  __syncthreads();

  // ---- softmax over rows; each wave owns 4 rows (16 lanes per row) ----
  const int nk = q0 + 16;             // written columns
  const int row = w * 4 + l4;
  float mx = -1e38f;
  for (int c = l15; c < nk; c += 16) mx = fmaxf(mx, sc[row][c]);
#pragma unroll
  for (int o = 8; o; o >>= 1) mx = fmaxf(mx, __shfl_xor(mx, o, 64));
  float sum = 0.f;
  for (int c = l15; c < nk; c += 16) {
    float e = __expf(sc[row][c] - mx);
    sc[row][c] = e;                   // unnormalized probs; 1/sum applied at epilogue
    sum += e;
  }
#pragma unroll
  for (int o = 8; o; o >>= 1) sum += __shfl_xor(sum, o, 64);
  if (l15 == 0) inv[row] = 1.f / sum;
  // zero-pad to 32-key MFMA granularity when (qt+1)*16 % 32 != 0
  if (!(qt & 1)) sc[row][nk + l15] = 0.f;
  __syncthreads();

  // ---- PV: wave owns d-range [w*64, w*64+64) ----
  f32x4 o_acc[4];
#pragma unroll
  for (int i = 0; i < 4; i++) o_acc[i] = (f32x4){0.f, 0.f, 0.f, 0.f};
  const int nchunks = (qt + 2) >> 1;  // ceil((qt+1)*16 / 32)
  for (int c32 = 0; c32 < nchunks; c32++) {
    int k0 = c32 * 32;
    bf16x8 pf;
#pragma unroll
    for (int j = 0; j < 8; j++)
      pf[j] = (bf16)sc[l15][k0 + l4 * 8 + j];
#pragma unroll
    for (int ni = 0; ni < 4; ni++) {
      bf16x8 vf;
#pragma unroll
      for (int j = 0; j < 8; j++)
        vf[j] = qkv[(size_t)(k0 + l4 * 8 + j) * D3 + 2 * DIM + h * HDIM + w * 64 + ni * 16 + l15];
      o_acc[ni] = __builtin_amdgcn_mfma_f32_16x16x32_bf16(pf, vf, o_acc[ni], 0, 0, 0);
    }
  }
#pragma unroll
  for (int ni = 0; ni < 4; ni++) {
#pragma unroll
    for (int r = 0; r < 4; r++) {
      int qrow = l4 * 4 + r;
      float val = o_acc[ni][r] * inv[qrow];
      attn[(size_t)(q0 + qrow) * DIM + h * HDIM + w * 64 + ni * 16 + l15] = (bf16)val;
    }
  }
}

// ---------------- launch ----------------
// Workspace layout (peak 176 MiB, fits previously-proven 192 MiB budget):
//   [0,96M)    wT slot: w_qkvT(96M) -> w_denseT(32M) -> fc1/fc2 half-T (64M, alternating)
//   [64M,96M)  h1 half (32M) -- inside wT slot tail, free once w_qkvT is dead
//   [96M,112M) x1 (16M), then attn (16M) after x1 is dead
//   [112M,128M) x2 (16M)
//   [128M,176M) qkv (48M), then dense_o (32M) at [144M,176M) after qkv is dead
extern "C" void kernel_launch(void* const* d_in, const int* in_sizes, int n_in,
                              void* d_out, int out_size, void* d_ws, size_t ws_size,
                              hipStream_t stream)
{
  const float* hidden  = (const float*)d_in[0];
  const float* ln1w    = (const float*)d_in[1];
  const float* ln1b    = (const float*)d_in[2];
  const float* ln2w    = (const float*)d_in[3];
  const float* ln2b    = (const float*)d_in[4];
  const float* w_qkv   = (const float*)d_in[5];
  const float* b_qkv   = (const float*)d_in[6];
  const float* w_dense = (const float*)d_in[7];
  const float* b_dense = (const float*)d_in[8];
  const float* w_fc1   = (const float*)d_in[9];
  const float* b_fc1   = (const float*)d_in[10];
  const float* w_fc2   = (const float*)d_in[11];
  const float* b_fc2   = (const float*)d_in[12];

  char* ws = (char*)d_ws;
  bf16*  wT      = (bf16*)(ws);                      // transposed-weight slot
  bf16*  h1      = (bf16*)(ws + 67108864);           // 32 MiB (fc1 output half)
  bf16*  x1      = (bf16*)(ws + 100663296);          // 16 MiB
  bf16*  attn    = (bf16*)(ws + 100663296);          // reuses x1 (dead after QKV)
  bf16*  x2      = (bf16*)(ws + 117440512);          // 16 MiB
  bf16*  qkv     = (bf16*)(ws + 134217728);          // 48 MiB
  float* dense_o = (float*)(ws + 150994944);         // 32 MiB (reuses qkv tail)
  float* out     = (float*)d_out;

  hipFuncSetAttribute(reinterpret_cast<const void*>(attn_kernel),
                      hipFuncAttributeMaxDynamicSharedMemorySize, 131264);

  ln_kernel<<<SEQ, 256, 0, stream>>>(hidden, ln1w, ln1b, ln2w, ln2b, x1, x2);

  // w_qkv^T : [4096,12288] f32 -> [12288,4096] bf16
  transpose_kernel<<<dim3(DIM/64, D3/64), 256, 0, stream>>>(w_qkv, wT, D3, 0, 0, DIM);
  // QKV: x1[2048,4096] x w_qkvT -> qkv bf16
  gemm_kernel<0><<<dim3(16, 96), 256, 0, stream>>>(
      x1, wT, b_qkv, nullptr, nullptr, (void*)qkv, SEQ, D3, DIM);

  // w_dense^T : [4096,4096] -> bf16
  transpose_kernel<<<dim3(DIM/64, DIM/64), 256, 0, stream>>>(w_dense, wT, DIM, 0, 0, DIM);

  attn_kernel<<<dim3(SEQ / 16, NHEAD), 256, 131264, stream>>>(qkv, attn);

  // dense: attn x w_denseT -> dense_o f32
  gemm_kernel<1><<<dim3(16, 32), 256, 0, stream>>>(
      attn, wT, b_dense, nullptr, nullptr, (void*)dense_o, SEQ, DIM, DIM);

  // fc1/fc2 in two DFF halves; wT slot (64 MiB) time-shared between them.
  for (int hf = 0; hf < 2; hf++) {
    // w_fc1[:, hf*8192 : +8192]^T -> [8192,4096] bf16
    transpose_kernel<<<dim3(DIM/64, DHALF/64), 256, 0, stream>>>(
        w_fc1, wT, DFF_N, 0, hf * DHALF, DIM);
    // fc1 half + gelu: x2 x wT -> h1 bf16 [2048,8192]
    gemm_kernel<2><<<dim3(16, 64), 256, 0, stream>>>(
        x2, wT, b_fc1 + hf * DHALF, nullptr, nullptr, (void*)h1, SEQ, DHALF, DIM);
    // w_fc2[hf*8192 : +8192, :]^T -> [4096,8192] bf16
    transpose_kernel<<<dim3(DHALF/64, DIM/64), 256, 0, stream>>>(
        w_fc2, wT, DIM, hf * DHALF, 0, DHALF);
    if (hf == 0) {
      // fc2 half0 + bias + residuals: h1 x wT + dense_o + hidden -> out f32
      gemm_kernel<3><<<dim3(16, 32), 256, 0, stream>>>(
          h1, wT, b_fc2, dense_o, hidden, (void*)out, SEQ, DIM, DHALF);
    } else {
      // fc2 half1: out += h1 x wT
      gemm_kernel<4><<<dim3(16, 32), 256, 0, stream>>>(
          h1, wT, nullptr, nullptr, nullptr, (void*)out, SEQ, DIM, DHALF);
    }
  }
}